// Round 8
// baseline (250.942 us; speedup 1.0000x reference)
//
#include <hip/hip_runtime.h>
#include <stdint.h>

#define S_LEN 512
#define I_DIM 28
#define H_DIM 128
#define O_DIM 28
#define BT    32   // TWO independent 16-row groups per block

typedef __attribute__((ext_vector_type(8))) short bf16x8;
typedef __attribute__((ext_vector_type(4))) float f32x4;

static __device__ __forceinline__ short f2bf(float f) {   // cold paths only
    unsigned u = __float_as_uint(f);
    u = (u + 0x7fffu + ((u >> 16) & 1u)) >> 16;
    return (short)u;
}
static __device__ __forceinline__ float bf2f(unsigned short u) {
    return __uint_as_float(((unsigned)u) << 16);
}
static __device__ __forceinline__ unsigned cvt_pk(float a, float b) {
    unsigned r;
    asm("v_cvt_pk_bf16_f32 %0, %1, %2" : "=v"(r) : "v"(a), "v"(b));
    return r;
}
// tanh(a) = 1 - 2/(1+e^{2a}) : 2 trans + 3 VALU (validated R1-R7)
#define TWO_LOG2E 2.8853900817779268f
static __device__ __forceinline__ float fast_tanh(float a) {
    float e = __builtin_amdgcn_exp2f(a * TWO_LOG2E);
    float r = __builtin_amdgcn_rcpf(1.0f + e);
    return fmaf(-2.0f, r, 1.0f);
}

__global__ __launch_bounds__(512, 1) void rnn_fused(
    const float* __restrict__ x,
    const float* __restrict__ W_ih, const float* __restrict__ b_ih,
    const float* __restrict__ W_hh, const float* __restrict__ b_hh,
    const float* __restrict__ W_ho, const float* __restrict__ b_ho,
    float* __restrict__ out)
{
    const int tid  = threadIdx.x;
    const int wave = tid >> 6;
    const int g    = wave >> 2;        // group 0/1 (independent batch rows)
    const int w    = wave & 3;         // chunk owner within group
    const int lane = tid & 63;
    const int l15  = lane & 15;        // batch-row slot
    const int lk   = lane >> 4;        // 0..3 k-group
    const int r0   = blockIdx.x * BT + g * 16;

    // per-group h^T B-fragments (double buffered) + x B-frag rings. 32 KB.
    __shared__ __align__(16) bf16x8 hx[2][2][4][64];    // [buf][grp][chunk][lane]
    __shared__ __align__(16) bf16x8 xring[2][8][64];    // [grp][frame][lane]

    // ---- stationary A-fragments, wave-relative chunk order (R7-validated) ----
    // Tile T covers j(m) = 32w + 8*(m>>2) + 4T + (m&3); C reg r -> j = 32w+8lk+4T+r.
    bf16x8 Arel[2][4];
    bf16x8 Aih[2];
    f32x4  biasv[2];
    const int jmA = 32 * w + ((l15 >> 2) << 3) + (l15 & 3);
    #pragma unroll
    for (int T = 0; T < 2; ++T) {
        const int jA = jmA + 4 * T;
        #pragma unroll
        for (int q = 0; q < 4; ++q) {
            const int kc = (w + q) & 3;
            #pragma unroll
            for (int e = 0; e < 8; ++e)
                Arel[T][q][e] = f2bf(W_hh[(kc * 32 + lk * 8 + e) * H_DIM + jA]);
        }
        #pragma unroll
        for (int e = 0; e < 8; ++e) {
            int i = lk * 8 + e;
            Aih[T][e] = (i < I_DIM) ? f2bf(W_ih[i * H_DIM + jA]) : (short)0;
        }
        #pragma unroll
        for (int r = 0; r < 4; ++r) {
            int jC = 32 * w + lk * 8 + 4 * T + r;
            biasv[T][r] = b_ih[jC] + b_hh[jC];
        }
    }

    // group-local bases (uniform per wave)
    const bf16x8* rbase[2] = { &hx[0][g][0][0], &hx[1][g][0][0] };   // by PAR
    bf16x8*       wslot[2] = { &hx[1][g][w][0], &hx[0][g][w][0] };   // by PAR
    bf16x8*       xrg      = &xring[g][0][0];

    // foreign-chunk element offsets within rbase[PAR]
    const int o1 = ((w + 1) & 3) * 64 + lane;
    const int o2 = ((w + 2) & 3) * 64 + lane;
    const int o3 = ((w + 3) & 3) * 64 + lane;

    // h0 = 0 (LDS chunk + register copy)
    bf16x8 bown = {0,0,0,0,0,0,0,0};
    hx[0][g][w][lane] = bown;

    const bool hasHi = (lk < 3);       // k-group 3: only i=24..27 valid
    const float* xbase = x + (size_t)(r0 + l15) * S_LEN * I_DIM + lk * 8;

    // ---- prologue: wave (g,w) stages x frame w of its group ----
    {
        const float* src = xbase + w * I_DIM;
        float4 lo = *(const float4*)src;
        float4 hi = hasHi ? *(const float4*)(src + 4) : make_float4(0.f,0.f,0.f,0.f);
        union { bf16x8 v; unsigned u[4]; } fr;
        fr.u[0] = cvt_pk(lo.x, lo.y); fr.u[1] = cvt_pk(lo.z, lo.w);
        fr.u[2] = cvt_pk(hi.x, hi.y); fr.u[3] = cvt_pk(hi.z, hi.w);
        xrg[w * 64 + lane] = fr.v;
    }
    asm volatile("s_waitcnt lgkmcnt(0)" ::: "memory");
    __builtin_amdgcn_s_barrier();
    asm volatile("" ::: "memory");

    bf16x8 xcur = xrg[lane];

// One step (R7-validated). PAR/P compile-time literals.
#define RSTEP(PAR, P)                                                          \
    {                                                                          \
        const bf16x8* hxp = rbase[PAR];                                        \
        bf16x8 g1 = hxp[o1];                                                   \
        bf16x8 g2 = hxp[o2];                                                   \
        bf16x8 g3 = hxp[o3];                                                   \
        bf16x8 xnext = xrg[((t4 + P + 1) & 7) * 64 + lane];                    \
        if (P == 0 && tf < S_LEN) {                                            \
            const float* src = xbase + (size_t)tf * I_DIM;                     \
            pf_lo = *(const float4*)src;                                       \
            if (hasHi) pf_hi = *(const float4*)(src + 4);                      \
        }                                                                      \
        f32x4 a0 = biasv[0], a1 = biasv[1];                                    \
        a0 = __builtin_amdgcn_mfma_f32_16x16x32_bf16(Aih[0],     xcur, a0, 0,0,0); \
        a1 = __builtin_amdgcn_mfma_f32_16x16x32_bf16(Aih[1],     xcur, a1, 0,0,0); \
        a0 = __builtin_amdgcn_mfma_f32_16x16x32_bf16(Arel[0][0], bown, a0, 0,0,0); \
        a1 = __builtin_amdgcn_mfma_f32_16x16x32_bf16(Arel[1][0], bown, a1, 0,0,0); \
        f32x4 c0 = {0.f,0.f,0.f,0.f}, c1 = {0.f,0.f,0.f,0.f};                  \
        c0 = __builtin_amdgcn_mfma_f32_16x16x32_bf16(Arel[0][1], g1, c0, 0,0,0); \
        c1 = __builtin_amdgcn_mfma_f32_16x16x32_bf16(Arel[1][1], g1, c1, 0,0,0); \
        a0 = __builtin_amdgcn_mfma_f32_16x16x32_bf16(Arel[0][2], g2, a0, 0,0,0); \
        a1 = __builtin_amdgcn_mfma_f32_16x16x32_bf16(Arel[1][2], g2, a1, 0,0,0); \
        c0 = __builtin_amdgcn_mfma_f32_16x16x32_bf16(Arel[0][3], g3, c0, 0,0,0); \
        c1 = __builtin_amdgcn_mfma_f32_16x16x32_bf16(Arel[1][3], g3, c1, 0,0,0); \
        if (P == 2 && tf < S_LEN) {                                            \
            union { bf16x8 v; unsigned u[4]; } fr;                             \
            fr.u[0] = cvt_pk(pf_lo.x, pf_lo.y); fr.u[1] = cvt_pk(pf_lo.z, pf_lo.w); \
            fr.u[2] = cvt_pk(pf_hi.x, pf_hi.y); fr.u[3] = cvt_pk(pf_hi.z, pf_hi.w); \
            xrg[(tf & 7) * 64 + lane] = fr.v;                                  \
        }                                                                      \
        f32x4 s0 = a0 + c0, s1 = a1 + c1;                                      \
        float h0_ = fast_tanh(s0[0]), h1_ = fast_tanh(s0[1]);                  \
        float h2_ = fast_tanh(s0[2]), h3_ = fast_tanh(s0[3]);                  \
        float h4_ = fast_tanh(s1[0]), h5_ = fast_tanh(s1[1]);                  \
        float h6_ = fast_tanh(s1[2]), h7_ = fast_tanh(s1[3]);                  \
        union { bf16x8 v; unsigned u[4]; } hf;                                 \
        hf.u[0] = cvt_pk(h0_, h1_); hf.u[1] = cvt_pk(h2_, h3_);                \
        hf.u[2] = cvt_pk(h4_, h5_); hf.u[3] = cvt_pk(h6_, h7_);                \
        wslot[PAR][lane] = hf.v;                                               \
        bown = hf.v;                                                           \
        asm volatile("s_waitcnt lgkmcnt(0)" ::: "memory");                     \
        __builtin_amdgcn_s_barrier();                                          \
        asm volatile("" ::: "memory");                                        \
        xcur = xnext;                                                          \
    }

    for (int t4 = 0; t4 < S_LEN; t4 += 4) {
        const int tf = t4 + 4 + w;                 // x frame this wave stages
        float4 pf_lo = make_float4(0.f,0.f,0.f,0.f), pf_hi = pf_lo;
        RSTEP(0, 0)
        RSTEP(1, 1)
        RSTEP(0, 2)
        RSTEP(1, 3)
    }
#undef RSTEP

    // ---- epilogue: out = h_512 @ W_ho + b_ho ; final h in hx[0][grp] ----
    // h[b][j]: chunk j>>5, lane ((j>>3)&3)*16 + b, halfword j&7
    for (int idx = tid; idx < BT * O_DIM; idx += 512) {
        const int row = idx / O_DIM;               // 0..31
        const int o   = idx - row * O_DIM;
        const int grp = row >> 4;
        const int b   = row & 15;
        float sum = b_ho[o];
        const unsigned short* hb = (const unsigned short*)&hx[0][grp][0][0];
        #pragma unroll 4
        for (int j = 0; j < H_DIM; ++j) {
            int slot = (j >> 5) * 64 + ((j >> 3) & 3) * 16 + b;
            sum += bf2f(hb[slot * 8 + (j & 7)]) * W_ho[j * O_DIM + o];
        }
        out[(size_t)(blockIdx.x * BT + row) * O_DIM + o] = sum;
    }
}

extern "C" void kernel_launch(void* const* d_in, const int* in_sizes, int n_in,
                              void* d_out, int out_size, void* d_ws, size_t ws_size,
                              hipStream_t stream) {
    const float* x    = (const float*)d_in[0];
    const float* W_ih = (const float*)d_in[1];
    const float* b_ih = (const float*)d_in[2];
    const float* W_hh = (const float*)d_in[3];
    const float* b_hh = (const float*)d_in[4];
    const float* W_ho = (const float*)d_in[5];
    const float* b_ho = (const float*)d_in[6];
    const int B = in_sizes[0] / (S_LEN * I_DIM);   // 4096
    rnn_fused<<<B / BT, 512, 0, stream>>>(x, W_ih, b_ih, W_hh, b_hh, W_ho, b_ho,
                                          (float*)d_out);
}

// Round 9
// 199.592 us; speedup vs baseline: 1.2573x; 1.2573x over previous
//
#include <hip/hip_runtime.h>
#include <stdint.h>

#define S_LEN 512
#define I_DIM 28
#define H_DIM 128
#define O_DIM 28
#define BT    16   // batch rows per block

typedef __attribute__((ext_vector_type(8))) short bf16x8;
typedef __attribute__((ext_vector_type(4))) float f32x4;

static __device__ __forceinline__ short f2bf(float f) {   // cold paths only
    unsigned u = __float_as_uint(f);
    u = (u + 0x7fffu + ((u >> 16) & 1u)) >> 16;
    return (short)u;
}
static __device__ __forceinline__ float bf2f(unsigned short u) {
    return __uint_as_float(((unsigned)u) << 16);
}
static __device__ __forceinline__ unsigned cvt_pk(float a, float b) {
    unsigned r;
    asm("v_cvt_pk_bf16_f32 %0, %1, %2" : "=v"(r) : "v"(a), "v"(b));
    return r;
}
// tanh(a) = 1 - 2/(1+e^{2a}) : 2 trans + 3 VALU (validated R1-R8; LUT/poly lose)
#define TWO_LOG2E 2.8853900817779268f
static __device__ __forceinline__ float fast_tanh(float a) {
    float e = __builtin_amdgcn_exp2f(a * TWO_LOG2E);
    float r = __builtin_amdgcn_rcpf(1.0f + e);
    return fmaf(-2.0f, r, 1.0f);
}

__global__ __launch_bounds__(256, 1) void rnn_fused(
    const float* __restrict__ x,
    const float* __restrict__ W_ih, const float* __restrict__ b_ih,
    const float* __restrict__ W_hh, const float* __restrict__ b_hh,
    const float* __restrict__ W_ho, const float* __restrict__ b_ho,
    float* __restrict__ out)
{
    const int tid  = threadIdx.x;
    const int wave = tid >> 6;         // 0..3 -> owns h-chunk wave (cols 32w..32w+31)
    const int lane = tid & 63;
    const int l15  = lane & 15;        // batch-row slot
    const int lk   = lane >> 4;        // 0..3 k-group
    const int r0   = blockIdx.x * BT;

    // h^T B-fragments by chunk, double buffered (8 KB); x B-frag ring (8 KB)
    __shared__ __align__(16) bf16x8 hx[2][4][64];
    __shared__ __align__(16) bf16x8 xring[8][64];

    // ---- stationary A-fragments, wave-relative chunk order (R7-validated) ----
    // Tile T covers j(m) = 32w + 8*(m>>2) + 4T + (m&3); C reg r -> j = 32w+8lk+4T+r.
    bf16x8 Arel[2][4];
    bf16x8 Aih[2];
    f32x4  biasv[2];
    const int jmA = 32 * wave + ((l15 >> 2) << 3) + (l15 & 3);
    #pragma unroll
    for (int T = 0; T < 2; ++T) {
        const int jA = jmA + 4 * T;
        #pragma unroll
        for (int q = 0; q < 4; ++q) {
            const int kc = (wave + q) & 3;
            #pragma unroll
            for (int e = 0; e < 8; ++e)
                Arel[T][q][e] = f2bf(W_hh[(kc * 32 + lk * 8 + e) * H_DIM + jA]);
        }
        #pragma unroll
        for (int e = 0; e < 8; ++e) {
            int i = lk * 8 + e;
            Aih[T][e] = (i < I_DIM) ? f2bf(W_ih[i * H_DIM + jA]) : (short)0;
        }
        #pragma unroll
        for (int r = 0; r < 4; ++r) {
            int jC = 32 * wave + lk * 8 + 4 * T + r;
            biasv[T][r] = b_ih[jC] + b_hh[jC];
        }
    }

    // foreign-chunk LDS slot offsets (elements into hx[par])
    const int o1 = ((wave + 1) & 3) * 64 + lane;
    const int o2 = ((wave + 2) & 3) * 64 + lane;
    const int o3 = ((wave + 3) & 3) * 64 + lane;

    // h0 = 0: LDS chunk + register copy
    bf16x8 bown = {0,0,0,0,0,0,0,0};
    hx[0][wave][lane] = bown;

    const bool hasHi = (lk < 3);       // k-group 3: only i=24..27 valid
    const float* xbase = x + (size_t)(r0 + l15) * S_LEN * I_DIM + lk * 8;

    // ---- prologue: wave w stages x frame w (frames 0..3) ----
    {
        const float* src = xbase + wave * I_DIM;
        float4 lo = *(const float4*)src;
        float4 hi = hasHi ? *(const float4*)(src + 4) : make_float4(0.f,0.f,0.f,0.f);
        union { bf16x8 v; unsigned u[4]; } fr;
        fr.u[0] = cvt_pk(lo.x, lo.y); fr.u[1] = cvt_pk(lo.z, lo.w);
        fr.u[2] = cvt_pk(hi.x, hi.y); fr.u[3] = cvt_pk(hi.z, hi.w);
        xring[wave][lane] = fr.v;
    }
    asm volatile("s_waitcnt lgkmcnt(0)" ::: "memory");
    __builtin_amdgcn_s_barrier();
    asm volatile("" ::: "memory");

    // hoisted x-projection accumulators for the UPCOMING step:
    // xacc = bias + Aih . x_t   (computed one step ahead, off the critical path)
    f32x4 xacc0, xacc1;
    {
        bf16x8 x0 = xring[0][lane];
        xacc0 = biasv[0];
        xacc1 = biasv[1];
        xacc0 = __builtin_amdgcn_mfma_f32_16x16x32_bf16(Aih[0], x0, xacc0, 0,0,0);
        xacc1 = __builtin_amdgcn_mfma_f32_16x16x32_bf16(Aih[1], x0, xacc1, 0,0,0);
    }

// One step. PAR/P compile-time literals.
// Entering: xacc0/1 already hold bias + Aih.x_t. Step opens with foreign reads
// + next-x read, covers ds latency with reg-only own-chunk MFMAs, and computes
// NEXT step's xacc during this step's tanh window (MFMA pipe idle there).
#define RSTEP(PAR, P)                                                          \
    {                                                                          \
        const bf16x8* hxp = &hx[PAR][0][0];                                    \
        bf16x8 g1 = hxp[o1];                                                   \
        bf16x8 g2 = hxp[o2];                                                   \
        bf16x8 g3 = hxp[o3];                                                   \
        bf16x8 xn = xring[(t4 + P + 1) & 7][lane];  /* safe: written >=1 barrier ago */ \
        if (P == 0 && tf < S_LEN) {                                            \
            const float* src = xbase + (size_t)tf * I_DIM;                     \
            pf_lo = *(const float4*)src;                                       \
            if (hasHi) pf_hi = *(const float4*)(src + 4);                      \
        }                                                                      \
        f32x4 a0 = xacc0, a1 = xacc1;                                          \
        a0 = __builtin_amdgcn_mfma_f32_16x16x32_bf16(Arel[0][0], bown, a0, 0,0,0); \
        a1 = __builtin_amdgcn_mfma_f32_16x16x32_bf16(Arel[1][0], bown, a1, 0,0,0); \
        f32x4 c0 = {0.f,0.f,0.f,0.f}, c1 = {0.f,0.f,0.f,0.f};                  \
        c0 = __builtin_amdgcn_mfma_f32_16x16x32_bf16(Arel[0][1], g1, c0, 0,0,0); \
        c1 = __builtin_amdgcn_mfma_f32_16x16x32_bf16(Arel[1][1], g1, c1, 0,0,0); \
        a0 = __builtin_amdgcn_mfma_f32_16x16x32_bf16(Arel[0][2], g2, a0, 0,0,0); \
        a1 = __builtin_amdgcn_mfma_f32_16x16x32_bf16(Arel[1][2], g2, a1, 0,0,0); \
        c0 = __builtin_amdgcn_mfma_f32_16x16x32_bf16(Arel[0][3], g3, c0, 0,0,0); \
        c1 = __builtin_amdgcn_mfma_f32_16x16x32_bf16(Arel[1][3], g3, c1, 0,0,0); \
        if (P == 2 && tf < S_LEN) {                                            \
            union { bf16x8 v; unsigned u[4]; } fr;                             \
            fr.u[0] = cvt_pk(pf_lo.x, pf_lo.y); fr.u[1] = cvt_pk(pf_lo.z, pf_lo.w); \
            fr.u[2] = cvt_pk(pf_hi.x, pf_hi.y); fr.u[3] = cvt_pk(pf_hi.z, pf_hi.w); \
            xring[tf & 7][lane] = fr.v;                                        \
        }                                                                      \
        f32x4 s0 = a0 + c0, s1 = a1 + c1;                                      \
        /* next step's x-projection: issues on MFMA pipe under the tanh trans */ \
        xacc0 = biasv[0];                                                      \
        xacc1 = biasv[1];                                                      \
        xacc0 = __builtin_amdgcn_mfma_f32_16x16x32_bf16(Aih[0], xn, xacc0, 0,0,0); \
        xacc1 = __builtin_amdgcn_mfma_f32_16x16x32_bf16(Aih[1], xn, xacc1, 0,0,0); \
        float h0_ = fast_tanh(s0[0]), h1_ = fast_tanh(s0[1]);                  \
        float h2_ = fast_tanh(s0[2]), h3_ = fast_tanh(s0[3]);                  \
        float h4_ = fast_tanh(s1[0]), h5_ = fast_tanh(s1[1]);                  \
        float h6_ = fast_tanh(s1[2]), h7_ = fast_tanh(s1[3]);                  \
        union { bf16x8 v; unsigned u[4]; } hf;                                 \
        hf.u[0] = cvt_pk(h0_, h1_); hf.u[1] = cvt_pk(h2_, h3_);                \
        hf.u[2] = cvt_pk(h4_, h5_); hf.u[3] = cvt_pk(h6_, h7_);                \
        hx[(PAR) ^ 1][wave][lane] = hf.v;                                      \
        bown = hf.v;                                                           \
        asm volatile("s_waitcnt lgkmcnt(0)" ::: "memory");                     \
        __builtin_amdgcn_s_barrier();                                          \
        asm volatile("" ::: "memory");                                        \
    }

    for (int t4 = 0; t4 < S_LEN; t4 += 4) {
        const int tf = t4 + 4 + wave;              // x frame this wave stages
        float4 pf_lo = make_float4(0.f,0.f,0.f,0.f), pf_hi = pf_lo;
        RSTEP(0, 0)
        RSTEP(1, 1)
        RSTEP(0, 2)
        RSTEP(1, 3)
    }
#undef RSTEP

    // ---- epilogue: out = h_512 @ W_ho + b_ho ; final h in hx[0] ----
    // h[b][j]: chunk j>>5, lane ((j>>3)&3)*16 + b, halfword j&7
    for (int idx = tid; idx < BT * O_DIM; idx += 256) {
        const int b = idx / O_DIM;
        const int o = idx - b * O_DIM;
        float sum = b_ho[o];
        const unsigned short* hb = (const unsigned short*)&hx[0][0][0];
        #pragma unroll 4
        for (int j = 0; j < H_DIM; ++j) {
            int slot = (j >> 5) * 64 + ((j >> 3) & 3) * 16 + b;
            sum += bf2f(hb[slot * 8 + (j & 7)]) * W_ho[j * O_DIM + o];
        }
        out[(size_t)(r0 + b) * O_DIM + o] = sum;
    }
}

extern "C" void kernel_launch(void* const* d_in, const int* in_sizes, int n_in,
                              void* d_out, int out_size, void* d_ws, size_t ws_size,
                              hipStream_t stream) {
    const float* x    = (const float*)d_in[0];
    const float* W_ih = (const float*)d_in[1];
    const float* b_ih = (const float*)d_in[2];
    const float* W_hh = (const float*)d_in[3];
    const float* b_hh = (const float*)d_in[4];
    const float* W_ho = (const float*)d_in[5];
    const float* b_ho = (const float*)d_in[6];
    const int B = in_sizes[0] / (S_LEN * I_DIM);   // 4096
    rnn_fused<<<B / BT, 256, 0, stream>>>(x, W_ih, b_ih, W_hh, b_hh, W_ho, b_ho,
                                          (float*)d_out);
}

// Round 10
// 183.181 us; speedup vs baseline: 1.3699x; 1.0896x over previous
//
#include <hip/hip_runtime.h>
#include <stdint.h>

#define S_LEN 512
#define I_DIM 28
#define H_DIM 128
#define O_DIM 28
#define BT    16   // batch rows per block; 8 waves, one 16-col tile per wave

typedef __attribute__((ext_vector_type(8))) short bf16x8;
typedef __attribute__((ext_vector_type(4))) float f32x4;

static __device__ __forceinline__ short f2bf(float f) {   // cold paths only
    unsigned u = __float_as_uint(f);
    u = (u + 0x7fffu + ((u >> 16) & 1u)) >> 16;
    return (short)u;
}
static __device__ __forceinline__ float bf2f(unsigned short u) {
    return __uint_as_float(((unsigned)u) << 16);
}
static __device__ __forceinline__ unsigned cvt_pk(float a, float b) {
    unsigned r;
    asm("v_cvt_pk_bf16_f32 %0, %1, %2" : "=v"(r) : "v"(a), "v"(b));
    return r;
}
// [5/4] Pade tanh + clamp: 1 trans + ~9 VALU; |err| <= ~1.1e-3 (< bf16 quant)
static __device__ __forceinline__ float pade_tanh(float x) {
    float u = x * x;
    float n = fmaf(u, fmaf(u, 1.0f, 105.0f), 945.0f) * x;
    float d = fmaf(u, fmaf(u, 15.0f, 420.0f), 945.0f);
    float t = n * __builtin_amdgcn_rcpf(d);
    return fminf(fmaxf(t, -1.0f), 1.0f);
}

__global__ __launch_bounds__(512, 1) void rnn_fused(
    const float* __restrict__ x,
    const float* __restrict__ W_ih, const float* __restrict__ b_ih,
    const float* __restrict__ W_hh, const float* __restrict__ b_hh,
    const float* __restrict__ W_ho, const float* __restrict__ b_ho,
    float* __restrict__ out)
{
    const int tid  = threadIdx.x;
    const int wave = tid >> 6;         // 0..7 -> owns cols [16w, 16w+16)
    const int lane = tid & 63;
    const int l15  = lane & 15;        // batch-row slot
    const int lk   = lane >> 4;        // 0..3 k-group
    const int r0   = blockIdx.x * BT;

    // h^T B-fragments by 32-col chunk, double buffered (8 KB); x ring (16 KB)
    __shared__ __align__(16) bf16x8 hx[2][4][64];
    __shared__ __align__(16) bf16x8 xring[16][64];

    // ---- stationary A-fragments (swapped form, identity column map) ----
    // A[m=l15][k=8lk+e] = W_hh[k][16w+l15]; C reg r -> j = 16w + 4lk + r, b = l15.
    bf16x8 Ahh0, Ahh1, Ahh2, Ahh3, Aih;
    f32x4  biasv;
    const int jA = 16 * wave + l15;
    #pragma unroll
    for (int e = 0; e < 8; ++e) {
        Ahh0[e] = f2bf(W_hh[(  0 + lk * 8 + e) * H_DIM + jA]);
        Ahh1[e] = f2bf(W_hh[( 32 + lk * 8 + e) * H_DIM + jA]);
        Ahh2[e] = f2bf(W_hh[( 64 + lk * 8 + e) * H_DIM + jA]);
        Ahh3[e] = f2bf(W_hh[( 96 + lk * 8 + e) * H_DIM + jA]);
        int i = lk * 8 + e;
        Aih[e] = (i < I_DIM) ? f2bf(W_ih[i * H_DIM + jA]) : (short)0;
    }
    #pragma unroll
    for (int r = 0; r < 4; ++r) {
        int jC = 16 * wave + lk * 4 + r;
        biasv[r] = b_ih[jC] + b_hh[jC];
    }

    // ds_write_b64 target: produced (j=16w+4lk+r, b=l15) -> chunk w>>1,
    // lane' = (2(w&1)+(lk>>1))*16 + l15, byte 8*(lk&1)
    const int wboff = (wave >> 1) * 1024
                    + ((2 * (wave & 1) + (lk >> 1)) * 16 + l15) * 16
                    + 8 * (lk & 1);

    // h0 = 0
    ((uint2*)&hx[0][0][0])[tid] = make_uint2(0u, 0u);

    const bool hasHi = (lk < 3);       // k-group 3: only i=24..27 valid
    const float* xbase = x + (size_t)(r0 + l15) * S_LEN * I_DIM + lk * 8;

    // ---- prologue: wave w stages x frame w (frames 0..7) ----
    {
        const float* src = xbase + wave * I_DIM;
        float4 lo = *(const float4*)src;
        float4 hi = hasHi ? *(const float4*)(src + 4) : make_float4(0.f,0.f,0.f,0.f);
        union { bf16x8 v; unsigned u[4]; } fr;
        fr.u[0] = cvt_pk(lo.x, lo.y); fr.u[1] = cvt_pk(lo.z, lo.w);
        fr.u[2] = cvt_pk(hi.x, hi.y); fr.u[3] = cvt_pk(hi.z, hi.w);
        xring[wave][lane] = fr.v;
    }
    asm volatile("s_waitcnt lgkmcnt(0)" ::: "memory");
    __builtin_amdgcn_s_barrier();
    asm volatile("" ::: "memory");

// One step. PAR/P compile-time literals. Reads all 4 h-chunks + x frag, 5-MFMA
// (3+2 split), Pade tanh, one lane-local b64 write, drain, barrier.
#define RSTEP(PAR, P)                                                          \
    {                                                                          \
        const bf16x8* hxp = &hx[PAR][0][0];                                    \
        bf16x8 b0 = hxp[0 * 64 + lane];                                        \
        bf16x8 b1 = hxp[1 * 64 + lane];                                        \
        bf16x8 b2 = hxp[2 * 64 + lane];                                        \
        bf16x8 b3 = hxp[3 * 64 + lane];                                        \
        bf16x8 xc = xring[(t8 + P) & 15][lane];                                \
        if (P == 0 && doPf) {                                                  \
            const float* src = xbase + (size_t)tf * I_DIM;                     \
            pf_lo = *(const float4*)src;                                       \
            if (hasHi) pf_hi = *(const float4*)(src + 4);                      \
        }                                                                      \
        f32x4 a = biasv;                                                       \
        a = __builtin_amdgcn_mfma_f32_16x16x32_bf16(Aih,  xc, a, 0, 0, 0);     \
        a = __builtin_amdgcn_mfma_f32_16x16x32_bf16(Ahh0, b0, a, 0, 0, 0);     \
        a = __builtin_amdgcn_mfma_f32_16x16x32_bf16(Ahh1, b1, a, 0, 0, 0);     \
        f32x4 c = {0.f, 0.f, 0.f, 0.f};                                        \
        c = __builtin_amdgcn_mfma_f32_16x16x32_bf16(Ahh2, b2, c, 0, 0, 0);     \
        c = __builtin_amdgcn_mfma_f32_16x16x32_bf16(Ahh3, b3, c, 0, 0, 0);     \
        if (P == 2 && doPf) {                                                  \
            union { bf16x8 v; unsigned u[4]; } fr;                             \
            fr.u[0] = cvt_pk(pf_lo.x, pf_lo.y); fr.u[1] = cvt_pk(pf_lo.z, pf_lo.w); \
            fr.u[2] = cvt_pk(pf_hi.x, pf_hi.y); fr.u[3] = cvt_pk(pf_hi.z, pf_hi.w); \
            xring[tf & 15][lane] = fr.v;                                       \
        }                                                                      \
        f32x4 s = a + c;                                                       \
        float h0_ = pade_tanh(s[0]), h1_ = pade_tanh(s[1]);                    \
        float h2_ = pade_tanh(s[2]), h3_ = pade_tanh(s[3]);                    \
        uint2 wv;                                                              \
        wv.x = cvt_pk(h0_, h1_); wv.y = cvt_pk(h2_, h3_);                      \
        *(uint2*)((char*)&hx[(PAR) ^ 1][0][0] + wboff) = wv;                   \
        asm volatile("s_waitcnt lgkmcnt(0)" ::: "memory");                     \
        __builtin_amdgcn_s_barrier();                                          \
        asm volatile("" ::: "memory");                                        \
    }

    for (int t8 = 0; t8 < S_LEN; t8 += 8) {
        const int tf   = t8 + 8 + wave;            // x frame this wave stages
        const bool doPf = (tf < S_LEN);
        float4 pf_lo = make_float4(0.f,0.f,0.f,0.f), pf_hi = pf_lo;
        RSTEP(0, 0)
        RSTEP(1, 1)
        RSTEP(0, 2)
        RSTEP(1, 3)
        RSTEP(0, 4)
        RSTEP(1, 5)
        RSTEP(0, 6)
        RSTEP(1, 7)
    }
#undef RSTEP

    // ---- epilogue: out = h_512 @ W_ho + b_ho ; final h in hx[0] ----
    // h[b][j]: chunk j>>5, lane ((j>>3)&3)*16 + b, halfword j&7
    for (int idx = tid; idx < BT * O_DIM; idx += 512) {
        const int b = idx / O_DIM;
        const int o = idx - b * O_DIM;
        float sum = b_ho[o];
        const unsigned short* hb = (const unsigned short*)&hx[0][0][0];
        #pragma unroll 4
        for (int j = 0; j < H_DIM; ++j) {
            int slot = (j >> 5) * 64 + ((j >> 3) & 3) * 16 + b;
            sum += bf2f(hb[slot * 8 + (j & 7)]) * W_ho[j * O_DIM + o];
        }
        out[(size_t)(r0 + b) * O_DIM + o] = sum;
    }
}

extern "C" void kernel_launch(void* const* d_in, const int* in_sizes, int n_in,
                              void* d_out, int out_size, void* d_ws, size_t ws_size,
                              hipStream_t stream) {
    const float* x    = (const float*)d_in[0];
    const float* W_ih = (const float*)d_in[1];
    const float* b_ih = (const float*)d_in[2];
    const float* W_hh = (const float*)d_in[3];
    const float* b_hh = (const float*)d_in[4];
    const float* W_ho = (const float*)d_in[5];
    const float* b_ho = (const float*)d_in[6];
    const int B = in_sizes[0] / (S_LEN * I_DIM);   // 4096
    rnn_fused<<<B / BT, 512, 0, stream>>>(x, W_ih, b_ih, W_hh, b_hh, W_ho, b_ho,
                                          (float*)d_out);
}

// Round 11
// 177.098 us; speedup vs baseline: 1.4170x; 1.0343x over previous
//
#include <hip/hip_runtime.h>
#include <stdint.h>

#define S_LEN 512
#define I_DIM 28
#define H_DIM 128
#define O_DIM 28
#define BT    16   // batch rows per block; 8 waves, one 16-col tile per wave

typedef __attribute__((ext_vector_type(8))) short bf16x8;
typedef __attribute__((ext_vector_type(4))) float f32x4;

static __device__ __forceinline__ short f2bf(float f) {   // cold paths only
    unsigned u = __float_as_uint(f);
    u = (u + 0x7fffu + ((u >> 16) & 1u)) >> 16;
    return (short)u;
}
static __device__ __forceinline__ float bf2f(unsigned short u) {
    return __uint_as_float(((unsigned)u) << 16);
}
static __device__ __forceinline__ unsigned cvt_pk(float a, float b) {
    unsigned r;
    asm("v_cvt_pk_bf16_f32 %0, %1, %2" : "=v"(r) : "v"(a), "v"(b));
    return r;
}
// [5/4] Pade tanh + clamp: 1 trans + ~9 VALU; |err| <= ~1.1e-3 (< bf16 quant)
static __device__ __forceinline__ float pade_tanh(float x) {
    float u = x * x;
    float n = fmaf(u, fmaf(u, 1.0f, 105.0f), 945.0f) * x;
    float d = fmaf(u, fmaf(u, 15.0f, 420.0f), 945.0f);
    float t = n * __builtin_amdgcn_rcpf(d);
    return fminf(fmaxf(t, -1.0f), 1.0f);
}

__global__ __launch_bounds__(512, 1) void rnn_fused(
    const float* __restrict__ x,
    const float* __restrict__ W_ih, const float* __restrict__ b_ih,
    const float* __restrict__ W_hh, const float* __restrict__ b_hh,
    const float* __restrict__ W_ho, const float* __restrict__ b_ho,
    float* __restrict__ out)
{
    const int tid  = threadIdx.x;
    const int wave = tid >> 6;         // 0..7 -> owns cols [16w, 16w+16)
    const int lane = tid & 63;
    const int l15  = lane & 15;        // batch-row slot
    const int lk   = lane >> 4;        // 0..3 k-group
    const int r0   = blockIdx.x * BT;

    // h^T B-fragments by 32-col chunk, double buffered (8 KB); x ring (16 KB)
    __shared__ __align__(16) bf16x8 hx[2][4][64];
    __shared__ __align__(16) bf16x8 xring[16][64];

    // ---- stationary A-fragments (swapped form, identity column map) ----
    // A[m=l15][k=8lk+e] = W_hh[k][16w+l15]; C reg r -> j = 16w + 4lk + r, b = l15.
    bf16x8 Ahh0, Ahh1, Ahh2, Ahh3, Aih;
    f32x4  biasv;
    const int jA = 16 * wave + l15;
    #pragma unroll
    for (int e = 0; e < 8; ++e) {
        Ahh0[e] = f2bf(W_hh[(  0 + lk * 8 + e) * H_DIM + jA]);
        Ahh1[e] = f2bf(W_hh[( 32 + lk * 8 + e) * H_DIM + jA]);
        Ahh2[e] = f2bf(W_hh[( 64 + lk * 8 + e) * H_DIM + jA]);
        Ahh3[e] = f2bf(W_hh[( 96 + lk * 8 + e) * H_DIM + jA]);
        int i = lk * 8 + e;
        Aih[e] = (i < I_DIM) ? f2bf(W_ih[i * H_DIM + jA]) : (short)0;
    }
    #pragma unroll
    for (int r = 0; r < 4; ++r) {
        int jC = 16 * wave + lk * 4 + r;
        biasv[r] = b_ih[jC] + b_hh[jC];
    }

    // ds_write target: produced (j=16w+4lk+r, b=l15) -> chunk w>>1,
    // lane' = (2(w&1)+(lk>>1))*16 + l15, byte 8*(lk&1)
    const int wboff = (wave >> 1) * 1024
                    + ((2 * (wave & 1) + (lk >> 1)) * 16 + l15) * 16
                    + 8 * (lk & 1);

    // h0 = 0
    ((uint2*)&hx[0][0][0])[tid] = make_uint2(0u, 0u);

    const bool hasHi = (lk < 3);       // k-group 3: only i=24..27 valid
    const float* xbase = x + (size_t)(r0 + l15) * S_LEN * I_DIM + lk * 8;

    // ---- prologue: wave w stages x frame w (frames 0..7) ----
    {
        const float* src = xbase + wave * I_DIM;
        float4 lo = *(const float4*)src;
        float4 hi = hasHi ? *(const float4*)(src + 4) : make_float4(0.f,0.f,0.f,0.f);
        union { bf16x8 v; unsigned u[4]; } fr;
        fr.u[0] = cvt_pk(lo.x, lo.y); fr.u[1] = cvt_pk(lo.z, lo.w);
        fr.u[2] = cvt_pk(hi.x, hi.y); fr.u[3] = cvt_pk(hi.z, hi.w);
        xring[wave][lane] = fr.v;
    }
    asm volatile("s_waitcnt lgkmcnt(0)" ::: "memory");
    __builtin_amdgcn_s_barrier();
    asm volatile("" ::: "memory");

    // hoisted x-projection accumulator for the upcoming step:
    // xacc = bias + Aih . x_t  (always computed one step ahead, off the path)
    f32x4 xacc;
    {
        bf16x8 x0 = xring[0][lane];
        xacc = biasv;
        xacc = __builtin_amdgcn_mfma_f32_16x16x32_bf16(Aih, x0, xacc, 0, 0, 0);
    }

// One step. PAR/P compile-time literals. Entering: xacc = bias + Aih.x_t.
// Reads 4 h-chunks + next x-frag (latency-batched), 4-MFMA (2+2 split),
// computes next xacc under the tanh window, early half-writes, drain, barrier.
#define RSTEP(PAR, P)                                                          \
    {                                                                          \
        const bf16x8* hxp = &hx[PAR][0][0];                                    \
        bf16x8 b0 = hxp[0 * 64 + lane];                                        \
        bf16x8 b1 = hxp[1 * 64 + lane];                                        \
        bf16x8 b2 = hxp[2 * 64 + lane];                                        \
        bf16x8 b3 = hxp[3 * 64 + lane];                                        \
        bf16x8 xn = xring[(t8 + P + 1) & 15][lane]; /* slot written >=1 barrier ago */ \
        if (P == 0 && doPf) {                                                  \
            const float* src = xbase + (size_t)tf * I_DIM;                     \
            pf_lo = *(const float4*)src;                                       \
            if (hasHi) pf_hi = *(const float4*)(src + 4);                      \
        }                                                                      \
        f32x4 a = xacc;                                                        \
        a = __builtin_amdgcn_mfma_f32_16x16x32_bf16(Ahh0, b0, a, 0, 0, 0);     \
        a = __builtin_amdgcn_mfma_f32_16x16x32_bf16(Ahh1, b1, a, 0, 0, 0);     \
        f32x4 c = {0.f, 0.f, 0.f, 0.f};                                        \
        c = __builtin_amdgcn_mfma_f32_16x16x32_bf16(Ahh2, b2, c, 0, 0, 0);     \
        c = __builtin_amdgcn_mfma_f32_16x16x32_bf16(Ahh3, b3, c, 0, 0, 0);     \
        if (P == 2 && doPf) {                                                  \
            union { bf16x8 v; unsigned u[4]; } fr;                             \
            fr.u[0] = cvt_pk(pf_lo.x, pf_lo.y); fr.u[1] = cvt_pk(pf_lo.z, pf_lo.w); \
            fr.u[2] = cvt_pk(pf_hi.x, pf_hi.y); fr.u[3] = cvt_pk(pf_hi.z, pf_hi.w); \
            xring[tf & 15][lane] = fr.v;                                       \
        }                                                                      \
        f32x4 s = a + c;                                                       \
        /* next step's x-projection: MFMA pipe is idle during tanh */          \
        xacc = biasv;                                                          \
        xacc = __builtin_amdgcn_mfma_f32_16x16x32_bf16(Aih, xn, xacc, 0, 0, 0);\
        char* wb = (char*)&hx[(PAR) ^ 1][0][0] + wboff;                        \
        float h0_ = pade_tanh(s[0]), h1_ = pade_tanh(s[1]);                    \
        *(unsigned*)(wb)     = cvt_pk(h0_, h1_);   /* early half-write */      \
        float h2_ = pade_tanh(s[2]), h3_ = pade_tanh(s[3]);                    \
        *(unsigned*)(wb + 4) = cvt_pk(h2_, h3_);                               \
        asm volatile("s_waitcnt lgkmcnt(0)" ::: "memory");                     \
        __builtin_amdgcn_s_barrier();                                          \
        asm volatile("" ::: "memory");                                        \
    }

    for (int t8 = 0; t8 < S_LEN; t8 += 8) {
        const int tf   = t8 + 8 + wave;            // x frame this wave stages
        const bool doPf = (tf < S_LEN);
        float4 pf_lo = make_float4(0.f,0.f,0.f,0.f), pf_hi = pf_lo;
        RSTEP(0, 0)
        RSTEP(1, 1)
        RSTEP(0, 2)
        RSTEP(1, 3)
        RSTEP(0, 4)
        RSTEP(1, 5)
        RSTEP(0, 6)
        RSTEP(1, 7)
    }
#undef RSTEP

    // ---- epilogue: out = h_512 @ W_ho + b_ho ; final h in hx[0] ----
    // h[b][j]: chunk j>>5, lane ((j>>3)&3)*16 + b, halfword j&7
    for (int idx = tid; idx < BT * O_DIM; idx += 512) {
        const int b = idx / O_DIM;
        const int o = idx - b * O_DIM;
        float sum = b_ho[o];
        const unsigned short* hb = (const unsigned short*)&hx[0][0][0];
        #pragma unroll 4
        for (int j = 0; j < H_DIM; ++j) {
            int slot = (j >> 5) * 64 + ((j >> 3) & 3) * 16 + b;
            sum += bf2f(hb[slot * 8 + (j & 7)]) * W_ho[j * O_DIM + o];
        }
        out[(size_t)(r0 + b) * O_DIM + o] = sum;
    }
}

extern "C" void kernel_launch(void* const* d_in, const int* in_sizes, int n_in,
                              void* d_out, int out_size, void* d_ws, size_t ws_size,
                              hipStream_t stream) {
    const float* x    = (const float*)d_in[0];
    const float* W_ih = (const float*)d_in[1];
    const float* b_ih = (const float*)d_in[2];
    const float* W_hh = (const float*)d_in[3];
    const float* b_hh = (const float*)d_in[4];
    const float* W_ho = (const float*)d_in[5];
    const float* b_ho = (const float*)d_in[6];
    const int B = in_sizes[0] / (S_LEN * I_DIM);   // 4096
    rnn_fused<<<B / BT, 512, 0, stream>>>(x, W_ih, b_ih, W_hh, b_hh, W_ho, b_ho,
                                          (float*)d_out);
}

// Round 12
// 161.375 us; speedup vs baseline: 1.5550x; 1.0974x over previous
//
#include <hip/hip_runtime.h>
#include <stdint.h>

#define S_LEN 512
#define I_DIM 28
#define H_DIM 128
#define O_DIM 28
#define BT    16   // batch rows per block; 8 waves, one 16-col tile per wave

typedef __attribute__((ext_vector_type(8))) short bf16x8;
typedef __attribute__((ext_vector_type(4))) float f32x4;

static __device__ __forceinline__ short f2bf(float f) {   // cold paths only
    unsigned u = __float_as_uint(f);
    u = (u + 0x7fffu + ((u >> 16) & 1u)) >> 16;
    return (short)u;
}
static __device__ __forceinline__ float bf2f(unsigned short u) {
    return __uint_as_float(((unsigned)u) << 16);
}
static __device__ __forceinline__ unsigned cvt_pk(float a, float b) {
    unsigned r;
    asm("v_cvt_pk_bf16_f32 %0, %1, %2" : "=v"(r) : "v"(a), "v"(b));
    return r;
}
// [5/4] Pade tanh on 4 values via packed-f32 (v_pk_*): ~18 pk/VALU + 4 trans.
// |err| <= ~1.1e-3 (< bf16 quant). Validated numerically R10/R11.
static __device__ __forceinline__ f32x4 pade_tanh4(f32x4 x) {
    f32x4 u = x * x;
    f32x4 n = __builtin_elementwise_fma(u, u + 105.0f, (f32x4)(945.0f)) * x;
    f32x4 d = __builtin_elementwise_fma(
                  u, __builtin_elementwise_fma(u, (f32x4)(15.0f), (f32x4)(420.0f)),
                  (f32x4)(945.0f));
    f32x4 r;
    r[0] = __builtin_amdgcn_rcpf(d[0]); r[1] = __builtin_amdgcn_rcpf(d[1]);
    r[2] = __builtin_amdgcn_rcpf(d[2]); r[3] = __builtin_amdgcn_rcpf(d[3]);
    f32x4 t = n * r;
    t = __builtin_elementwise_max(t, (f32x4)(-1.0f));
    t = __builtin_elementwise_min(t, (f32x4)(1.0f));
    return t;
}

__global__ __launch_bounds__(512, 1) void rnn_fused(
    const float* __restrict__ x,
    const float* __restrict__ W_ih, const float* __restrict__ b_ih,
    const float* __restrict__ W_hh, const float* __restrict__ b_hh,
    const float* __restrict__ W_ho, const float* __restrict__ b_ho,
    float* __restrict__ out)
{
    const int tid  = threadIdx.x;
    const int wave = tid >> 6;         // 0..7 -> owns cols [16w, 16w+16)
    const int lane = tid & 63;
    const int l15  = lane & 15;        // batch-row slot
    const int lk   = lane >> 4;        // 0..3 k-group
    const int r0   = blockIdx.x * BT;

    // h^T B-fragments by 32-col chunk, double buffered (8 KB); x ring (16 KB)
    __shared__ __align__(16) bf16x8 hx[2][4][64];
    __shared__ __align__(16) bf16x8 xring[16][64];

    // ---- stationary A-fragments (swapped form, identity column map) ----
    // A[m=l15][k=8lk+e] = W_hh[k][16w+l15]; C reg r -> j = 16w + 4lk + r, b = l15.
    bf16x8 Ahh0, Ahh1, Ahh2, Ahh3, Aih;
    f32x4  biasv;
    const int jA = 16 * wave + l15;
    #pragma unroll
    for (int e = 0; e < 8; ++e) {
        Ahh0[e] = f2bf(W_hh[(  0 + lk * 8 + e) * H_DIM + jA]);
        Ahh1[e] = f2bf(W_hh[( 32 + lk * 8 + e) * H_DIM + jA]);
        Ahh2[e] = f2bf(W_hh[( 64 + lk * 8 + e) * H_DIM + jA]);
        Ahh3[e] = f2bf(W_hh[( 96 + lk * 8 + e) * H_DIM + jA]);
        int i = lk * 8 + e;
        Aih[e] = (i < I_DIM) ? f2bf(W_ih[i * H_DIM + jA]) : (short)0;
    }
    #pragma unroll
    for (int r = 0; r < 4; ++r) {
        int jC = 16 * wave + lk * 4 + r;
        biasv[r] = b_ih[jC] + b_hh[jC];
    }

    // ds_write target: produced (j=16w+4lk+r, b=l15) -> chunk w>>1,
    // lane' = (2(w&1)+(lk>>1))*16 + l15, byte 8*(lk&1)
    const int wboff = (wave >> 1) * 1024
                    + ((2 * (wave & 1) + (lk >> 1)) * 16 + l15) * 16
                    + 8 * (lk & 1);

    // h0 = 0
    ((uint2*)&hx[0][0][0])[tid] = make_uint2(0u, 0u);

    const bool hasHi = (lk < 3);       // k-group 3: only i=24..27 valid
    const float* xbase = x + (size_t)(r0 + l15) * S_LEN * I_DIM + lk * 8;

    // ---- prologue: wave w stages x frame w (frames 0..7) ----
    {
        const float* src = xbase + wave * I_DIM;
        float4 lo = *(const float4*)src;
        float4 hi = hasHi ? *(const float4*)(src + 4) : make_float4(0.f,0.f,0.f,0.f);
        union { bf16x8 v; unsigned u[4]; } fr;
        fr.u[0] = cvt_pk(lo.x, lo.y); fr.u[1] = cvt_pk(lo.z, lo.w);
        fr.u[2] = cvt_pk(hi.x, hi.y); fr.u[3] = cvt_pk(hi.z, hi.w);
        xring[wave][lane] = fr.v;
    }
    asm volatile("s_waitcnt lgkmcnt(0)" ::: "memory");
    __builtin_amdgcn_s_barrier();
    asm volatile("" ::: "memory");

    // hoisted x-projection accumulator for the upcoming step:
    // xacc = bias + Aih . x_t  (always computed one step ahead, off the path)
    f32x4 xacc;
    {
        bf16x8 x0 = xring[0][lane];
        xacc = biasv;
        xacc = __builtin_amdgcn_mfma_f32_16x16x32_bf16(Aih, x0, xacc, 0, 0, 0);
    }

// One step. PAR/P compile-time literals. Entering: xacc = bias + Aih.x_t.
// Reads 4 h-chunks + next x-frag (latency-batched), 4-MFMA (2+2 split),
// computes next xacc under the packed tanh window, b64 write, drain, barrier.
#define RSTEP(PAR, P)                                                          \
    {                                                                          \
        const bf16x8* hxp = &hx[PAR][0][0];                                    \
        bf16x8 b0 = hxp[0 * 64 + lane];                                        \
        bf16x8 b1 = hxp[1 * 64 + lane];                                        \
        bf16x8 b2 = hxp[2 * 64 + lane];                                        \
        bf16x8 b3 = hxp[3 * 64 + lane];                                        \
        bf16x8 xn = xring[(t8 + P + 1) & 15][lane]; /* slot written >=1 barrier ago */ \
        if (P == 0 && doPf) {                                                  \
            const float* src = xbase + (size_t)tf * I_DIM;                     \
            pf_lo = *(const float4*)src;                                       \
            if (hasHi) pf_hi = *(const float4*)(src + 4);                      \
        }                                                                      \
        f32x4 a = xacc;                                                        \
        a = __builtin_amdgcn_mfma_f32_16x16x32_bf16(Ahh0, b0, a, 0, 0, 0);     \
        a = __builtin_amdgcn_mfma_f32_16x16x32_bf16(Ahh1, b1, a, 0, 0, 0);     \
        f32x4 c = {0.f, 0.f, 0.f, 0.f};                                        \
        c = __builtin_amdgcn_mfma_f32_16x16x32_bf16(Ahh2, b2, c, 0, 0, 0);     \
        c = __builtin_amdgcn_mfma_f32_16x16x32_bf16(Ahh3, b3, c, 0, 0, 0);     \
        if (P == 2 && doPf) {                                                  \
            union { bf16x8 v; unsigned u[4]; } fr;                             \
            fr.u[0] = cvt_pk(pf_lo.x, pf_lo.y); fr.u[1] = cvt_pk(pf_lo.z, pf_lo.w); \
            fr.u[2] = cvt_pk(pf_hi.x, pf_hi.y); fr.u[3] = cvt_pk(pf_hi.z, pf_hi.w); \
            xring[tf & 15][lane] = fr.v;                                       \
        }                                                                      \
        f32x4 s = a + c;                                                       \
        /* next step's x-projection: MFMA pipe is idle during tanh */          \
        xacc = biasv;                                                          \
        xacc = __builtin_amdgcn_mfma_f32_16x16x32_bf16(Aih, xn, xacc, 0, 0, 0);\
        f32x4 h = pade_tanh4(s);                                               \
        uint2 wv;                                                              \
        wv.x = cvt_pk(h[0], h[1]); wv.y = cvt_pk(h[2], h[3]);                  \
        *(uint2*)((char*)&hx[(PAR) ^ 1][0][0] + wboff) = wv;                   \
        asm volatile("s_waitcnt lgkmcnt(0)" ::: "memory");                     \
        __builtin_amdgcn_s_barrier();                                          \
        asm volatile("" ::: "memory");                                        \
    }

    for (int t8 = 0; t8 < S_LEN; t8 += 8) {
        const int tf   = t8 + 8 + wave;            // x frame this wave stages
        const bool doPf = (tf < S_LEN);
        float4 pf_lo = make_float4(0.f,0.f,0.f,0.f), pf_hi = pf_lo;
        RSTEP(0, 0)
        RSTEP(1, 1)
        RSTEP(0, 2)
        RSTEP(1, 3)
        RSTEP(0, 4)
        RSTEP(1, 5)
        RSTEP(0, 6)
        RSTEP(1, 7)
    }
#undef RSTEP

    // ---- epilogue: out = h_512 @ W_ho + b_ho ; final h in hx[0] ----
    // h[b][j]: chunk j>>5, lane ((j>>3)&3)*16 + b, halfword j&7
    for (int idx = tid; idx < BT * O_DIM; idx += 512) {
        const int b = idx / O_DIM;
        const int o = idx - b * O_DIM;
        float sum = b_ho[o];
        const unsigned short* hb = (const unsigned short*)&hx[0][0][0];
        #pragma unroll 4
        for (int j = 0; j < H_DIM; ++j) {
            int slot = (j >> 5) * 64 + ((j >> 3) & 3) * 16 + b;
            sum += bf2f(hb[slot * 8 + (j & 7)]) * W_ho[j * O_DIM + o];
        }
        out[(size_t)(r0 + b) * O_DIM + o] = sum;
    }
}

extern "C" void kernel_launch(void* const* d_in, const int* in_sizes, int n_in,
                              void* d_out, int out_size, void* d_ws, size_t ws_size,
                              hipStream_t stream) {
    const float* x    = (const float*)d_in[0];
    const float* W_ih = (const float*)d_in[1];
    const float* b_ih = (const float*)d_in[2];
    const float* W_hh = (const float*)d_in[3];
    const float* b_hh = (const float*)d_in[4];
    const float* W_ho = (const float*)d_in[5];
    const float* b_ho = (const float*)d_in[6];
    const int B = in_sizes[0] / (S_LEN * I_DIM);   // 4096
    rnn_fused<<<B / BT, 512, 0, stream>>>(x, W_ih, b_ih, W_hh, b_hh, W_ho, b_ho,
                                          (float*)d_out);
}